// Round 10
// baseline (116.897 us; speedup 1.0000x reference)
//
#include <hip/hip_runtime.h>

// ============================================================================
// FUSED kernel v3 (R10). Block = 384 thr (6 waves) = 96 k-rows = 4 batches.
// Phase 1: k staged global->LDS with 256-B-contiguous-per-row load segments
//   (4 rows x 256B per instruction), per-wave private double-buffered 64-col
//   units; MFMA fragments read from LDS (ds_read_b128, padded rows). Split-bf16
//   3-term (hi*hi + hi*lo + lo*hi) as before. Tests the hypothesis that the
//   16x64B@2KB-stride fragment-direct loads were capping HBM at ~4.2 TB/s.
// Phase 2: unchanged proven tail (waves 0..3, one batch each).
// Fallback: R3 fused one-wave kernel when B % 4 != 0.
// ============================================================================

typedef short s16x8 __attribute__((ext_vector_type(8)));
typedef float f32x4 __attribute__((ext_vector_type(4)));

__device__ __forceinline__ unsigned perm_hi(float a, float b) {
  // D = (a.hi16 << 16) | b.hi16  (bf16-truncate two floats, packed)
  return __builtin_amdgcn_perm(__float_as_uint(a), __float_as_uint(b), 0x07060302u);
}

// ---- 32-lane-local cross-lane helpers ----
#define DPP_ADD(x, ctrl, rmask)                                                   \
  x += __int_as_float(__builtin_amdgcn_update_dpp(                                \
      0, __float_as_int(x), ctrl, rmask, 0xF, false))

__device__ __forceinline__ float wave_sum64(float x) {
  DPP_ADD(x, 0xB1, 0xF);
  DPP_ADD(x, 0x4E, 0xF);
  DPP_ADD(x, 0x141, 0xF);
  DPP_ADD(x, 0x140, 0xF);
  DPP_ADD(x, 0x142, 0xA);
  DPP_ADD(x, 0x143, 0xC);
  return x;  // full sum valid in lanes 48..63
}

#define DPP_BF(x, OP, ctrl)                                                       \
  {                                                                               \
    float _t = __int_as_float(__builtin_amdgcn_update_dpp(                        \
        0, __float_as_int(x), ctrl, 0xF, 0xF, true));                             \
    x = OP(x, _t);                                                                \
  }
__device__ __forceinline__ float bf32_max(float x) {
  DPP_BF(x, fmaxf, 0xB1);
  DPP_BF(x, fmaxf, 0x4E);
  DPP_BF(x, fmaxf, 0x141);
  DPP_BF(x, fmaxf, 0x140);
  float t = __int_as_float(__builtin_amdgcn_ds_swizzle(__float_as_int(x), 0x401F));
  return fmaxf(x, t);
}
__device__ __forceinline__ float bf32_add(float x) {
  DPP_ADD(x, 0xB1, 0xF);
  DPP_ADD(x, 0x4E, 0xF);
  DPP_ADD(x, 0x141, 0xF);
  DPP_ADD(x, 0x140, 0xF);
  float t = __int_as_float(__builtin_amdgcn_ds_swizzle(__float_as_int(x), 0x401F));
  return x + t;
}

__device__ __forceinline__ float dot12(const float* a, float4 b0, float4 b1, float4 b2) {
  return a[0] * b0.x + a[1] * b0.y + a[2] * b0.z + a[3] * b0.w +
         a[4] * b1.x + a[5] * b1.y + a[6] * b1.z + a[7] * b1.w +
         a[8] * b2.x + a[9] * b2.y + a[10] * b2.z + a[11] * b2.w;
}

// ---------------------------------------------------------------------------
// Fused kernel v3
// ---------------------------------------------------------------------------
__global__ __launch_bounds__(384, 3) void coattn_fused(
    const float* __restrict__ q, const float* __restrict__ k,
    const float* __restrict__ Wq, const float* __restrict__ bq,
    const float* __restrict__ Wk, const float* __restrict__ bk,
    const float* __restrict__ Wl, const float* __restrict__ bl,
    float* __restrict__ out) {
  constexpr int WPADS = 520;   // shorts per Wk row (1040 B)
  constexpr int KSTRF = 68;    // floats per staged k-row (272 B: 256 + 16 pad)

  // Region W: Wk hi|lo staging (24,960 B); kpL[96][12] (4,608 B) overlaid after
  //           the end-of-phase-1 barrier.
  // Region K: per-wave k staging, 6 waves x 2 units x 16 rows x 272 B = 52,224 B;
  //           qcS/GS (15,360 B) overlaid in phase 2.
  __shared__ alignas(16) char smemW[12 * WPADS * 2 * 2];        // 24,960 B
  __shared__ alignas(16) char smemK[6 * 2 * 16 * KSTRF * 4];    // 52,224 B

  short* lwk_hi = (short*)smemW;
  short* lwk_lo = (short*)(smemW + 12 * WPADS * 2);

  const int tid = threadIdx.x;
  const int wave = tid >> 6;
  const int lane = tid & 63;

  // ---- stage Wk -> LDS as bf16 hi + residual lo ----
  for (int i = tid; i < 12 * 512; i += 384) {
    const int e = i >> 9, d = i & 511;
    const float f = Wk[i];
    const unsigned u = __float_as_uint(f);
    const float lo = f - __uint_as_float(u & 0xFFFF0000u);
    lwk_hi[e * WPADS + d] = (short)(u >> 16);
    lwk_lo[e * WPADS + d] = (short)(__float_as_uint(lo) >> 16);
  }
  __syncthreads();

  // ---- Phase 1: k_proj. One 16-row tile per wave, K in 8 units of 64 cols ----
  const int rowL = lane & 15;
  const int kgrp = lane >> 4;                  // 0..3
  const int e_eff = (rowL < 12) ? rowL : 11;   // cols 12..15 discarded
  const int sub = lane >> 4;                   // load mapping: row-within-quad
  const int pos = lane & 15;                   //               16B position

  const int r0 = blockIdx.x * 96 + wave * 16;
  // contiguous-segment load base: lane covers bytes [pos*16, pos*16+16) of
  // row (r0 + 4*i + sub)'s 256-B unit slice
  const float* kg = k + (size_t)(r0 + sub) * 512 + pos * 4;
  float* kw = (float*)smemK + wave * (2 * 16 * KSTRF);

  f32x4 acc = {0.f, 0.f, 0.f, 0.f};

#define LOADU(R, C)                                                                \
  R##0 = *(const float4*)(kg + 0 * 2048 + (C)*64);                                 \
  R##1 = *(const float4*)(kg + 1 * 2048 + (C)*64);                                 \
  R##2 = *(const float4*)(kg + 2 * 2048 + (C)*64);                                 \
  R##3 = *(const float4*)(kg + 3 * 2048 + (C)*64);

#define WRITEU(R, BUF)                                                             \
  *(float4*)&kw[(BUF)*16 * KSTRF + (0 * 4 + sub) * KSTRF + pos * 4] = R##0;        \
  *(float4*)&kw[(BUF)*16 * KSTRF + (1 * 4 + sub) * KSTRF + pos * 4] = R##1;        \
  *(float4*)&kw[(BUF)*16 * KSTRF + (2 * 4 + sub) * KSTRF + pos * 4] = R##2;        \
  *(float4*)&kw[(BUF)*16 * KSTRF + (3 * 4 + sub) * KSTRF + pos * 4] = R##3;

#define STEP(C, S)                                                                 \
  {                                                                                \
    const float* kb = &kw[((C)&1) * 16 * KSTRF];                                   \
    float4 f0 = *(const float4*)&kb[rowL * KSTRF + kgrp * 8 + (S)*32];             \
    float4 f1 = *(const float4*)&kb[rowL * KSTRF + kgrp * 8 + (S)*32 + 4];         \
    s16x8 bhi = *(const s16x8*)(lwk_hi + e_eff * WPADS + kgrp * 8 + (2 * (C) + (S)) * 32); \
    s16x8 blo = *(const s16x8*)(lwk_lo + e_eff * WPADS + kgrp * 8 + (2 * (C) + (S)) * 32); \
    union { unsigned u[4]; s16x8 v; } ah, al;                                      \
    ah.u[0] = perm_hi(f0.y, f0.x);                                                 \
    ah.u[1] = perm_hi(f0.w, f0.z);                                                 \
    ah.u[2] = perm_hi(f1.y, f1.x);                                                 \
    ah.u[3] = perm_hi(f1.w, f1.z);                                                 \
    float l0 = f0.x - __uint_as_float(__float_as_uint(f0.x) & 0xFFFF0000u);        \
    float l1 = f0.y - __uint_as_float(__float_as_uint(f0.y) & 0xFFFF0000u);        \
    float l2 = f0.z - __uint_as_float(__float_as_uint(f0.z) & 0xFFFF0000u);        \
    float l3 = f0.w - __uint_as_float(__float_as_uint(f0.w) & 0xFFFF0000u);        \
    float l4 = f1.x - __uint_as_float(__float_as_uint(f1.x) & 0xFFFF0000u);        \
    float l5 = f1.y - __uint_as_float(__float_as_uint(f1.y) & 0xFFFF0000u);        \
    float l6 = f1.z - __uint_as_float(__float_as_uint(f1.z) & 0xFFFF0000u);        \
    float l7 = f1.w - __uint_as_float(__float_as_uint(f1.w) & 0xFFFF0000u);        \
    al.u[0] = perm_hi(l1, l0);                                                     \
    al.u[1] = perm_hi(l3, l2);                                                     \
    al.u[2] = perm_hi(l5, l4);                                                     \
    al.u[3] = perm_hi(l7, l6);                                                     \
    acc = __builtin_amdgcn_mfma_f32_16x16x32_bf16(ah.v, bhi, acc, 0, 0, 0);        \
    acc = __builtin_amdgcn_mfma_f32_16x16x32_bf16(ah.v, blo, acc, 0, 0, 0);        \
    acc = __builtin_amdgcn_mfma_f32_16x16x32_bf16(al.v, bhi, acc, 0, 0, 0);        \
  }

#define COMPUTE(C) STEP(C, 0) STEP(C, 1)

  {
    float4 X0, X1, X2, X3, Y0, Y1, Y2, Y3;
    // prologue: units 0,1 in flight; unit 0 -> buf0
    LOADU(X, 0)
    LOADU(Y, 1)
    WRITEU(X, 0)
    // steady state: write unit c+1, issue unit c+2, compute unit c
    LOADU(X, 2)  WRITEU(Y, 1)  COMPUTE(0)
    LOADU(Y, 3)  WRITEU(X, 0)  COMPUTE(1)
    LOADU(X, 4)  WRITEU(Y, 1)  COMPUTE(2)
    LOADU(Y, 5)  WRITEU(X, 0)  COMPUTE(3)
    LOADU(X, 6)  WRITEU(Y, 1)  COMPUTE(4)
    LOADU(Y, 7)  WRITEU(X, 0)  COMPUTE(5)
    WRITEU(Y, 1)  COMPUTE(6)
    COMPUTE(7)
  }
#undef LOADU
#undef WRITEU
#undef STEP
#undef COMPUTE

  // publish kp tile: D row = wave*16 + kgrp*4 + i, col = rowL (= e)
  __syncthreads();  // all phase-1 Wk reads done before kpL overlays region W
  float(*kpL)[12] = (float(*)[12])smemW;
  if (rowL < 12) {
    const int lr0 = wave * 16 + kgrp * 4;
#pragma unroll
    for (int i = 0; i < 4; ++i) kpL[lr0 + i][rowL] = acc[i];
  }
  __syncthreads();

  // ---- Phase 2: tail, waves 0..3, one batch each (proven R8 tail) ----
  if (wave < 4) {
    float(*qcS)[28] = (float(*)[28])(smemK + (size_t)wave * (24 * 28 * 4));
    float(*GS)[12] = (float(*)[12])(smemK + 4 * (24 * 28 * 4) + (size_t)wave * (24 * 12 * 4));

    const int b = blockIdx.x * 4 + wave;
    const int li = (lane < 24) ? lane : 0;
    const bool act = (lane < 24);
    const int kb0 = wave * 24;

    const float4* WqV = reinterpret_cast<const float4*>(Wq);
    const float4* WlV = reinterpret_cast<const float4*>(Wl);

    float qr[12];
    if (act) {
      const float4* qb = reinterpret_cast<const float4*>(q + (size_t)b * 288 + li * 12);
      float4 t0 = qb[0], t1 = qb[1], t2 = qb[2];
      qr[0] = t0.x; qr[1] = t0.y; qr[2] = t0.z; qr[3] = t0.w;
      qr[4] = t1.x; qr[5] = t1.y; qr[6] = t1.z; qr[7] = t1.w;
      qr[8] = t2.x; qr[9] = t2.y; qr[10] = t2.z; qr[11] = t2.w;
    } else {
#pragma unroll
      for (int d = 0; d < 12; ++d) qr[d] = 0.f;
    }

    float qp_[12];
#pragma unroll
    for (int e = 0; e < 12; ++e) {
      float4 w0 = WqV[e * 3 + 0], w1 = WqV[e * 3 + 1], w2 = WqV[e * 3 + 2];
      qp_[e] = bq[e] + dot12(qr, w0, w1, w2);
    }

    float qbk = 0.f;
#pragma unroll
    for (int e = 0; e < 12; ++e) qbk += qp_[e] * bk[e];

    float qkr[24];
#pragma unroll
    for (int kk = 0; kk < 24; ++kk) {
      float4 k0 = *(const float4*)&kpL[kb0 + kk][0];
      float4 k1 = *(const float4*)&kpL[kb0 + kk][4];
      float4 k2 = *(const float4*)&kpL[kb0 + kk][8];
      qkr[kk] = qbk + dot12(qp_, k0, k1, k2);
    }
    if (lane >= 24) {
#pragma unroll
      for (int j = 0; j < 24; ++j) qkr[j] = -1e30f;
    }

    float akr[24];
    {
      float rm = qkr[0];
#pragma unroll
      for (int j = 1; j < 24; ++j) rm = fmaxf(rm, qkr[j]);
      float s = 0.f;
#pragma unroll
      for (int j = 0; j < 24; ++j) {
        akr[j] = __expf(qkr[j] - rm);
        s += akr[j];
      }
      const float inv = __builtin_amdgcn_rcpf(s);
#pragma unroll
      for (int j = 0; j < 24; ++j) akr[j] *= inv;
    }

    if (lane < 32) {
#pragma unroll
      for (int j = 0; j < 24; ++j) {
        const float m = bf32_max(qkr[j]);
        const float t = __expf(qkr[j] - m);
        const float s2 = bf32_add(t);
        qkr[j] = t * __builtin_amdgcn_rcpf(s2);
      }
    }

    float sa = 0.f;
#pragma unroll
    for (int j = 0; j < 24; ++j) sa += qkr[j];
    float cq[12];
#pragma unroll
    for (int e = 0; e < 12; ++e) cq[e] = bk[e] * sa;
#pragma unroll
    for (int kk = 0; kk < 24; ++kk) {
      float4 k0 = *(const float4*)&kpL[kb0 + kk][0];
      float4 k1 = *(const float4*)&kpL[kb0 + kk][4];
      float4 k2 = *(const float4*)&kpL[kb0 + kk][8];
      const float a = qkr[kk];
      cq[0] += a * k0.x; cq[1] += a * k0.y; cq[2] += a * k0.z; cq[3] += a * k0.w;
      cq[4] += a * k1.x; cq[5] += a * k1.y; cq[6] += a * k1.z; cq[7] += a * k1.w;
      cq[8] += a * k2.x; cq[9] += a * k2.y; cq[10] += a * k2.z; cq[11] += a * k2.w;
    }

    float G[12];
#pragma unroll
    for (int d = 0; d < 12; ++d) {
      float4 w0 = WlV[d * 6 + 0], w1 = WlV[d * 6 + 1], w2 = WlV[d * 6 + 2];
      float4 w3 = WlV[d * 6 + 3], w4 = WlV[d * 6 + 4], w5 = WlV[d * 6 + 5];
      G[d] = akr[0] * w0.x + akr[1] * w0.y + akr[2] * w0.z + akr[3] * w0.w +
             akr[4] * w1.x + akr[5] * w1.y + akr[6] * w1.z + akr[7] * w1.w +
             akr[8] * w2.x + akr[9] * w2.y + akr[10] * w2.z + akr[11] * w2.w +
             akr[12] * w3.x + akr[13] * w3.y + akr[14] * w3.z + akr[15] * w3.w +
             akr[16] * w4.x + akr[17] * w4.y + akr[18] * w4.z + akr[19] * w4.w +
             akr[20] * w5.x + akr[21] * w5.y + akr[22] * w5.z + akr[23] * w5.w;
    }

    if (act) {
      float4 t;
      t.x = qr[0]; t.y = qr[1]; t.z = qr[2]; t.w = qr[3];
      *(float4*)&qcS[li][0] = t;
      t.x = qr[4]; t.y = qr[5]; t.z = qr[6]; t.w = qr[7];
      *(float4*)&qcS[li][4] = t;
      t.x = qr[8]; t.y = qr[9]; t.z = qr[10]; t.w = qr[11];
      *(float4*)&qcS[li][8] = t;
      t.x = cq[0]; t.y = cq[1]; t.z = cq[2]; t.w = cq[3];
      *(float4*)&qcS[li][12] = t;
      t.x = cq[4]; t.y = cq[5]; t.z = cq[6]; t.w = cq[7];
      *(float4*)&qcS[li][16] = t;
      t.x = cq[8]; t.y = cq[9]; t.z = cq[10]; t.w = cq[11];
      *(float4*)&qcS[li][20] = t;
      t.x = G[0]; t.y = G[1]; t.z = G[2]; t.w = G[3];
      *(float4*)&GS[li][0] = t;
      t.x = G[4]; t.y = G[5]; t.z = G[6]; t.w = G[7];
      *(float4*)&GS[li][4] = t;
      t.x = G[8]; t.y = G[9]; t.z = G[10]; t.w = G[11];
      *(float4*)&GS[li][8] = t;
    }

    if (act) {
      float accq[12];
#pragma unroll
      for (int d = 0; d < 12; ++d) accq[d] = bl[d];
#pragma unroll
      for (int q0 = 0; q0 < 24; ++q0) {
        const float qv = qcS[q0][li];
        float4 g0 = *(const float4*)&GS[q0][0];
        float4 g1 = *(const float4*)&GS[q0][4];
        float4 g2 = *(const float4*)&GS[q0][8];
        accq[0] += qv * g0.x; accq[1] += qv * g0.y; accq[2] += qv * g0.z; accq[3] += qv * g0.w;
        accq[4] += qv * g1.x; accq[5] += qv * g1.y; accq[6] += qv * g1.z; accq[7] += qv * g1.w;
        accq[8] += qv * g2.x; accq[9] += qv * g2.y; accq[10] += qv * g2.z; accq[11] += qv * g2.w;
      }
      float* ob = out + (size_t)b * 288 + li * 12;
      float4 w0, w1, w2;
      w0.x = accq[0]; w0.y = accq[1]; w0.z = accq[2]; w0.w = accq[3];
      w1.x = accq[4]; w1.y = accq[5]; w1.z = accq[6]; w1.w = accq[7];
      w2.x = accq[8]; w2.y = accq[9]; w2.z = accq[10]; w2.w = accq[11];
      *(float4*)(ob + 0) = w0;
      *(float4*)(ob + 4) = w1;
      *(float4*)(ob + 8) = w2;
    }
  }
}

// ---------------------------------------------------------------------------
// Fallback: R3 fused one-wave kernel (any B)
// ---------------------------------------------------------------------------
__global__ __launch_bounds__(64) void coattn_kernel(
    const float* __restrict__ q, const float* __restrict__ k,
    const float* __restrict__ Wq, const float* __restrict__ bq,
    const float* __restrict__ Wk, const float* __restrict__ bk,
    const float* __restrict__ Wl, const float* __restrict__ bl,
    float* __restrict__ out) {
  constexpr int QL = 24, KVL = 24, DQ = 12, DKV = 512;

  __shared__ alignas(16) float kp[KVL][DQ];
  __shared__ alignas(16) float qc[QL][24];
  __shared__ alignas(16) float akT[KVL][28];
  __shared__ alignas(16) float ckL[KVL][28];
  __shared__ alignas(16) float WqL[DQ][DQ];
  __shared__ alignas(16) float WlT[KVL][DQ];
  __shared__ alignas(16) float bqL[DQ], bkL[DQ], blL[DQ];

  const int lane = threadIdx.x;
  const int b = blockIdx.x;
  const int li = (lane < 24) ? lane : 0;

  for (int p = lane; p < DQ * DQ; p += 64) WqL[p / DQ][p % DQ] = Wq[p];
  for (int p = lane; p < DQ * KVL; p += 64) WlT[p % KVL][p / KVL] = Wl[p];
  const float* qb = q + (size_t)b * (QL * DQ);
  for (int p = lane; p < QL * DQ; p += 64) qc[p / DQ][p % DQ] = qb[p];
  if (lane < DQ) {
    bqL[lane] = bq[lane];
    bkL[lane] = bk[lane];
    blL[lane] = bl[lane];
  }

  const float4* WkV = reinterpret_cast<const float4*>(Wk);
  float4 wk0[DQ], wk1[DQ];
#pragma unroll
  for (int e = 0; e < DQ; ++e) {
    wk0[e] = WkV[e * 128 + lane];
    wk1[e] = WkV[e * 128 + 64 + lane];
  }

  const float4* kbV = reinterpret_cast<const float4*>(k + (size_t)b * (KVL * DKV));

#define KROW(AC, BC, ROW)                                                          \
  {                                                                                \
    float pp[DQ];                                                                  \
    _Pragma("unroll") for (int e = 0; e < DQ; ++e) {                               \
      pp[e] = (AC).x * wk0[e].x + (AC).y * wk0[e].y + (AC).z * wk0[e].z +          \
              (AC).w * wk0[e].w + (BC).x * wk1[e].x + (BC).y * wk1[e].y +          \
              (BC).z * wk1[e].z + (BC).w * wk1[e].w;                               \
    }                                                                              \
    _Pragma("unroll") for (int e = 0; e < DQ; ++e) pp[e] = wave_sum64(pp[e]);      \
    if (lane == 63) {                                                              \
      float4 w0, w1, w2;                                                           \
      w0.x = pp[0]; w0.y = pp[1]; w0.z = pp[2]; w0.w = pp[3];                      \
      w1.x = pp[4]; w1.y = pp[5]; w1.z = pp[6]; w1.w = pp[7];                      \
      w2.x = pp[8]; w2.y = pp[9]; w2.z = pp[10]; w2.w = pp[11];                    \
      *(float4*)&kp[ROW][0] = w0;                                                  \
      *(float4*)&kp[ROW][4] = w1;                                                  \
      *(float4*)&kp[ROW][8] = w2;                                                  \
    }                                                                              \
  }

  float4 A0 = kbV[0 * 128 + lane], B0 = kbV[0 * 128 + 64 + lane];
  float4 A1 = kbV[1 * 128 + lane], B1 = kbV[1 * 128 + 64 + lane];
  float4 A2, B2, A3, B3;
  for (int kv = 0; kv < KVL; kv += 4) {
    {
      const int r = kv + 2;
      A2 = kbV[r * 128 + lane];
      B2 = kbV[r * 128 + 64 + lane];
    }
    KROW(A0, B0, kv);
    {
      const int r = kv + 3;
      A3 = kbV[r * 128 + lane];
      B3 = kbV[r * 128 + 64 + lane];
    }
    KROW(A1, B1, kv + 1);
    {
      const int r = (kv + 4 < KVL) ? kv + 4 : KVL - 1;
      A0 = kbV[r * 128 + lane];
      B0 = kbV[r * 128 + 64 + lane];
    }
    KROW(A2, B2, kv + 2);
    {
      const int r = (kv + 5 < KVL) ? kv + 5 : KVL - 1;
      A1 = kbV[r * 128 + lane];
      B1 = kbV[r * 128 + 64 + lane];
    }
    KROW(A3, B3, kv + 3);
  }
#undef KROW

  float qr[DQ];
  {
    float4 t0 = *(const float4*)&qc[li][0];
    float4 t1 = *(const float4*)&qc[li][4];
    float4 t2 = *(const float4*)&qc[li][8];
    qr[0] = t0.x; qr[1] = t0.y; qr[2] = t0.z; qr[3] = t0.w;
    qr[4] = t1.x; qr[5] = t1.y; qr[6] = t1.z; qr[7] = t1.w;
    qr[8] = t2.x; qr[9] = t2.y; qr[10] = t2.z; qr[11] = t2.w;
  }
  float bqr[DQ];
  {
    float4 t0 = *(const float4*)&bqL[0];
    float4 t1 = *(const float4*)&bqL[4];
    float4 t2 = *(const float4*)&bqL[8];
    bqr[0] = t0.x; bqr[1] = t0.y; bqr[2] = t0.z; bqr[3] = t0.w;
    bqr[4] = t1.x; bqr[5] = t1.y; bqr[6] = t1.z; bqr[7] = t1.w;
    bqr[8] = t2.x; bqr[9] = t2.y; bqr[10] = t2.z; bqr[11] = t2.w;
  }
  float qp_[DQ];
#pragma unroll
  for (int e = 0; e < DQ; ++e) {
    float4 w0 = *(const float4*)&WqL[e][0];
    float4 w1 = *(const float4*)&WqL[e][4];
    float4 w2 = *(const float4*)&WqL[e][8];
    qp_[e] = bqr[e] + dot12(qr, w0, w1, w2);
  }

  float bkr[DQ];
  {
    float4 t0 = *(const float4*)&bkL[0];
    float4 t1 = *(const float4*)&bkL[4];
    float4 t2 = *(const float4*)&bkL[8];
    bkr[0] = t0.x; bkr[1] = t0.y; bkr[2] = t0.z; bkr[3] = t0.w;
    bkr[4] = t1.x; bkr[5] = t1.y; bkr[6] = t1.z; bkr[7] = t1.w;
    bkr[8] = t2.x; bkr[9] = t2.y; bkr[10] = t2.z; bkr[11] = t2.w;
  }
  float qbk = 0.f;
#pragma unroll
  for (int e = 0; e < DQ; ++e) qbk += qp_[e] * bkr[e];

  float qkr[KVL];
#pragma unroll
  for (int kk = 0; kk < KVL; ++kk) {
    float4 k0 = *(const float4*)&kp[kk][0];
    float4 k1 = *(const float4*)&kp[kk][4];
    float4 k2 = *(const float4*)&kp[kk][8];
    qkr[kk] = qbk + dot12(qp_, k0, k1, k2);
  }
  if (lane >= 24 && lane < 32) {
#pragma unroll
    for (int j = 0; j < KVL; ++j) qkr[j] = -1e30f;
  }

  float akr[KVL];
  {
    float rm = qkr[0];
#pragma unroll
    for (int j = 1; j < KVL; ++j) rm = fmaxf(rm, qkr[j]);
    float s = 0.f;
#pragma unroll
    for (int j = 0; j < KVL; ++j) {
      akr[j] = __expf(qkr[j] - rm);
      s += akr[j];
    }
    const float inv = __builtin_amdgcn_rcpf(s);
#pragma unroll
    for (int j = 0; j < KVL; ++j) akr[j] *= inv;
  }

#pragma unroll
  for (int j = 0; j < KVL; ++j) {
    const float m = bf32_max(qkr[j]);
    const float t = __expf(qkr[j] - m);
    const float s2 = bf32_add(t);
    qkr[j] = t * __builtin_amdgcn_rcpf(s2);
  }

  float sa = 0.f;
#pragma unroll
  for (int j = 0; j < KVL; ++j) sa += qkr[j];
  float cq[DQ];
#pragma unroll
  for (int e = 0; e < DQ; ++e) cq[e] = bkr[e] * sa;
#pragma unroll
  for (int kk = 0; kk < KVL; ++kk) {
    float4 k0 = *(const float4*)&kp[kk][0];
    float4 k1 = *(const float4*)&kp[kk][4];
    float4 k2 = *(const float4*)&kp[kk][8];
    const float a = qkr[kk];
    cq[0] += a * k0.x; cq[1] += a * k0.y; cq[2] += a * k0.z; cq[3] += a * k0.w;
    cq[4] += a * k1.x; cq[5] += a * k1.y; cq[6] += a * k1.z; cq[7] += a * k1.w;
    cq[8] += a * k2.x; cq[9] += a * k2.y; cq[10] += a * k2.z; cq[11] += a * k2.w;
  }
  if (lane < 24) {
    float4 w0, w1, w2;
    w0.x = cq[0]; w0.y = cq[1]; w0.z = cq[2]; w0.w = cq[3];
    w1.x = cq[4]; w1.y = cq[5]; w1.z = cq[6]; w1.w = cq[7];
    w2.x = cq[8]; w2.y = cq[9]; w2.z = cq[10]; w2.w = cq[11];
    *(float4*)&qc[li][12] = w0;
    *(float4*)&qc[li][16] = w1;
    *(float4*)&qc[li][20] = w2;
#pragma unroll
    for (int kk = 0; kk < KVL; ++kk) akT[kk][li] = akr[kk];
  }

  float ak[QL];
  {
    float4 a0 = *(const float4*)&akT[li][0];
    float4 a1 = *(const float4*)&akT[li][4];
    float4 a2 = *(const float4*)&akT[li][8];
    float4 a3 = *(const float4*)&akT[li][12];
    float4 a4 = *(const float4*)&akT[li][16];
    float4 a5 = *(const float4*)&akT[li][20];
    ak[0] = a0.x; ak[1] = a0.y; ak[2] = a0.z; ak[3] = a0.w;
    ak[4] = a1.x; ak[5] = a1.y; ak[6] = a1.z; ak[7] = a1.w;
    ak[8] = a2.x; ak[9] = a2.y; ak[10] = a2.z; ak[11] = a2.w;
    ak[12] = a3.x; ak[13] = a3.y; ak[14] = a3.z; ak[15] = a3.w;
    ak[16] = a4.x; ak[17] = a4.y; ak[18] = a4.z; ak[19] = a4.w;
    ak[20] = a5.x; ak[21] = a5.y; ak[22] = a5.z; ak[23] = a5.w;
  }
  float ck[24];
#pragma unroll
  for (int e = 0; e < 24; ++e) ck[e] = 0.f;
#pragma unroll
  for (int qq = 0; qq < QL; ++qq) {
    float4 c0 = *(const float4*)&qc[qq][0];
    float4 c1 = *(const float4*)&qc[qq][4];
    float4 c2 = *(const float4*)&qc[qq][8];
    float4 c3 = *(const float4*)&qc[qq][12];
    float4 c4 = *(const float4*)&qc[qq][16];
    float4 c5 = *(const float4*)&qc[qq][20];
    const float a = ak[qq];
    ck[0] += a * c0.x; ck[1] += a * c0.y; ck[2] += a * c0.z; ck[3] += a * c0.w;
    ck[4] += a * c1.x; ck[5] += a * c1.y; ck[6] += a * c1.z; ck[7] += a * c1.w;
    ck[8] += a * c2.x; ck[9] += a * c2.y; ck[10] += a * c2.z; ck[11] += a * c2.w;
    ck[12] += a * c3.x; ck[13] += a * c3.y; ck[14] += a * c3.z; ck[15] += a * c3.w;
    ck[16] += a * c4.x; ck[17] += a * c4.y; ck[18] += a * c4.z; ck[19] += a * c4.w;
    ck[20] += a * c5.x; ck[21] += a * c5.y; ck[22] += a * c5.z; ck[23] += a * c5.w;
  }
  if (lane < 24) {
    float4 w0, w1, w2, w3, w4, w5;
    w0.x = ck[0]; w0.y = ck[1]; w0.z = ck[2]; w0.w = ck[3];
    w1.x = ck[4]; w1.y = ck[5]; w1.z = ck[6]; w1.w = ck[7];
    w2.x = ck[8]; w2.y = ck[9]; w2.z = ck[10]; w2.w = ck[11];
    w3.x = ck[12]; w3.y = ck[13]; w3.z = ck[14]; w3.w = ck[15];
    w4.x = ck[16]; w4.y = ck[17]; w4.z = ck[18]; w4.w = ck[19];
    w5.x = ck[20]; w5.y = ck[21]; w5.z = ck[22]; w5.w = ck[23];
    *(float4*)&ckL[li][0] = w0;
    *(float4*)&ckL[li][4] = w1;
    *(float4*)&ckL[li][8] = w2;
    *(float4*)&ckL[li][12] = w3;
    *(float4*)&ckL[li][16] = w4;
    *(float4*)&ckL[li][20] = w5;
  }

  float acc[DQ];
  {
    float4 t0 = *(const float4*)&blL[0];
    float4 t1 = *(const float4*)&blL[4];
    float4 t2 = *(const float4*)&blL[8];
    acc[0] = t0.x; acc[1] = t0.y; acc[2] = t0.z; acc[3] = t0.w;
    acc[4] = t1.x; acc[5] = t1.y; acc[6] = t1.z; acc[7] = t1.w;
    acc[8] = t2.x; acc[9] = t2.y; acc[10] = t2.z; acc[11] = t2.w;
  }
#pragma unroll
  for (int kk = 0; kk < KVL; ++kk) {
    const float cv = ckL[kk][li];
    float4 w0 = *(const float4*)&WlT[kk][0];
    float4 w1 = *(const float4*)&WlT[kk][4];
    float4 w2 = *(const float4*)&WlT[kk][8];
    acc[0] += cv * w0.x; acc[1] += cv * w0.y; acc[2] += cv * w0.z; acc[3] += cv * w0.w;
    acc[4] += cv * w1.x; acc[5] += cv * w1.y; acc[6] += cv * w1.z; acc[7] += cv * w1.w;
    acc[8] += cv * w2.x; acc[9] += cv * w2.y; acc[10] += cv * w2.z; acc[11] += cv * w2.w;
  }
  if (lane < 24) {
    float* ob = out + (size_t)b * 288 + li * 12;
    float4 w0, w1, w2;
    w0.x = acc[0]; w0.y = acc[1]; w0.z = acc[2]; w0.w = acc[3];
    w1.x = acc[4]; w1.y = acc[5]; w1.z = acc[6]; w1.w = acc[7];
    w2.x = acc[8]; w2.y = acc[9]; w2.z = acc[10]; w2.w = acc[11];
    *(float4*)(ob + 0) = w0;
    *(float4*)(ob + 4) = w1;
    *(float4*)(ob + 8) = w2;
  }
}

extern "C" void kernel_launch(void* const* d_in, const int* in_sizes, int n_in,
                              void* d_out, int out_size, void* d_ws, size_t ws_size,
                              hipStream_t stream) {
  const float* q = (const float*)d_in[0];
  const float* k = (const float*)d_in[1];
  // d_in[2] = v : unused by the reference
  const float* Wq = (const float*)d_in[3];
  const float* bq = (const float*)d_in[4];
  const float* Wk = (const float*)d_in[5];
  const float* bk = (const float*)d_in[6];
  const float* Wl = (const float*)d_in[7];
  const float* bl = (const float*)d_in[8];
  float* out = (float*)d_out;

  const int B = in_sizes[0] / (24 * 12);

  if ((B % 4) == 0) {
    coattn_fused<<<B / 4, 384, 0, stream>>>(q, k, Wq, bq, Wk, bk, Wl, bl, out);
  } else {
    coattn_kernel<<<B, 64, 0, stream>>>(q, k, Wq, bq, Wk, bk, Wl, bl, out);
  }
}

// Round 11
// 105.115 us; speedup vs baseline: 1.1121x; 1.1121x over previous
//
#include <hip/hip_runtime.h>

// ============================================================================
// FUSED kernel v4 (R11). Identical to the proven R8 structure (depth-2
// ping-pong MFMA k_proj + 4-wave tail), with ONE change: all once-streamed
// traffic (k reads, q reads, out writes) uses NON-TEMPORAL loads/stores so the
// 402 MB k stream does not allocate/thrash L1/L2/L3. Weights keep caching.
// Fallback: R3 fused one-wave kernel when B % 4 != 0.
// ============================================================================

typedef short s16x8 __attribute__((ext_vector_type(8)));
typedef float f32x4 __attribute__((ext_vector_type(4)));
typedef float f32x4v __attribute__((ext_vector_type(4)));

__device__ __forceinline__ float4 ntload4(const float* p) {
  f32x4v v = __builtin_nontemporal_load((const f32x4v*)p);
  float4 r;
  r.x = v.x; r.y = v.y; r.z = v.z; r.w = v.w;
  return r;
}
__device__ __forceinline__ void ntstore4(float* p, float4 s) {
  f32x4v v;
  v.x = s.x; v.y = s.y; v.z = s.z; v.w = s.w;
  __builtin_nontemporal_store(v, (f32x4v*)p);
}

__device__ __forceinline__ unsigned perm_hi(float a, float b) {
  // D = (a.hi16 << 16) | b.hi16  (bf16-truncate two floats, packed)
  return __builtin_amdgcn_perm(__float_as_uint(a), __float_as_uint(b), 0x07060302u);
}

// ---- 32-lane-local cross-lane helpers ----
#define DPP_ADD(x, ctrl, rmask)                                                   \
  x += __int_as_float(__builtin_amdgcn_update_dpp(                                \
      0, __float_as_int(x), ctrl, rmask, 0xF, false))

__device__ __forceinline__ float wave_sum64(float x) {
  DPP_ADD(x, 0xB1, 0xF);
  DPP_ADD(x, 0x4E, 0xF);
  DPP_ADD(x, 0x141, 0xF);
  DPP_ADD(x, 0x140, 0xF);
  DPP_ADD(x, 0x142, 0xA);
  DPP_ADD(x, 0x143, 0xC);
  return x;  // full sum valid in lanes 48..63
}

#define DPP_BF(x, OP, ctrl)                                                       \
  {                                                                               \
    float _t = __int_as_float(__builtin_amdgcn_update_dpp(                        \
        0, __float_as_int(x), ctrl, 0xF, 0xF, true));                             \
    x = OP(x, _t);                                                                \
  }
__device__ __forceinline__ float bf32_max(float x) {
  DPP_BF(x, fmaxf, 0xB1);
  DPP_BF(x, fmaxf, 0x4E);
  DPP_BF(x, fmaxf, 0x141);
  DPP_BF(x, fmaxf, 0x140);
  float t = __int_as_float(__builtin_amdgcn_ds_swizzle(__float_as_int(x), 0x401F));
  return fmaxf(x, t);
}
__device__ __forceinline__ float bf32_add(float x) {
  DPP_ADD(x, 0xB1, 0xF);
  DPP_ADD(x, 0x4E, 0xF);
  DPP_ADD(x, 0x141, 0xF);
  DPP_ADD(x, 0x140, 0xF);
  float t = __int_as_float(__builtin_amdgcn_ds_swizzle(__float_as_int(x), 0x401F));
  return x + t;
}

__device__ __forceinline__ float dot12(const float* a, float4 b0, float4 b1, float4 b2) {
  return a[0] * b0.x + a[1] * b0.y + a[2] * b0.z + a[3] * b0.w +
         a[4] * b1.x + a[5] * b1.y + a[6] * b1.z + a[7] * b1.w +
         a[8] * b2.x + a[9] * b2.y + a[10] * b2.z + a[11] * b2.w;
}

// ---------------------------------------------------------------------------
// Fused kernel v4
// ---------------------------------------------------------------------------
__global__ __launch_bounds__(384, 3) void coattn_fused(
    const float* __restrict__ q, const float* __restrict__ k,
    const float* __restrict__ Wq, const float* __restrict__ bq,
    const float* __restrict__ Wk, const float* __restrict__ bk,
    const float* __restrict__ Wl, const float* __restrict__ bl,
    float* __restrict__ out) {
  constexpr int WPAD = 520;  // shorts per Wk row (1040B, keeps 16B alignment)

  // Phase-1 use: Wk hi | Wk lo staging (24,960 B).
  // Phase-2 overlay: qcS[4][24][28] then GS[4][24][12].
  __shared__ alignas(16) char smemA[12 * WPAD * 2 * 2];
  __shared__ alignas(16) float kpL[96][12];  // 4 batches x 24 rows x 12 (persists)

  short* lwk_hi = (short*)smemA;
  short* lwk_lo = (short*)(smemA + 12 * WPAD * 2);

  const int tid = threadIdx.x;
  const int wave = tid >> 6;
  const int lane = tid & 63;

  // ---- stage Wk -> LDS as bf16 hi + residual lo (cached loads: reused) ----
  for (int i = tid; i < 12 * 512; i += 384) {
    const int e = i >> 9, d = i & 511;
    const float f = Wk[i];
    const unsigned u = __float_as_uint(f);
    const float lo = f - __uint_as_float(u & 0xFFFF0000u);
    lwk_hi[e * WPAD + d] = (short)(u >> 16);
    lwk_lo[e * WPAD + d] = (short)(__float_as_uint(lo) >> 16);
  }
  __syncthreads();

  // ---- Phase 1: MFMA k_proj, one 16-row tile per wave, depth-2 ping-pong ----
  const int rowL = lane & 15;
  const int kgrp = lane >> 4;                  // 0..3
  const int e_eff = (rowL < 12) ? rowL : 11;   // cols 12..15 discarded

  const int r0 = blockIdx.x * 96 + wave * 16;
  const float* abase = k + (size_t)(r0 + rowL) * 512 + kgrp * 8;
  const short* bhi_base = &lwk_hi[e_eff * WPAD + kgrp * 8];
  const short* blo_base = &lwk_lo[e_eff * WPAD + kgrp * 8];

  f32x4 acc = {0.f, 0.f, 0.f, 0.f};

#define COMP(X0, X1, S)                                                            \
  {                                                                                \
    s16x8 bhi = *(const s16x8*)(bhi_base + (S)*32);                                \
    s16x8 blo = *(const s16x8*)(blo_base + (S)*32);                                \
    union { unsigned u[4]; s16x8 v; } ah, al;                                      \
    ah.u[0] = perm_hi((X0).y, (X0).x);                                             \
    ah.u[1] = perm_hi((X0).w, (X0).z);                                             \
    ah.u[2] = perm_hi((X1).y, (X1).x);                                             \
    ah.u[3] = perm_hi((X1).w, (X1).z);                                             \
    float l0 = (X0).x - __uint_as_float(__float_as_uint((X0).x) & 0xFFFF0000u);    \
    float l1 = (X0).y - __uint_as_float(__float_as_uint((X0).y) & 0xFFFF0000u);    \
    float l2 = (X0).z - __uint_as_float(__float_as_uint((X0).z) & 0xFFFF0000u);    \
    float l3 = (X0).w - __uint_as_float(__float_as_uint((X0).w) & 0xFFFF0000u);    \
    float l4 = (X1).x - __uint_as_float(__float_as_uint((X1).x) & 0xFFFF0000u);    \
    float l5 = (X1).y - __uint_as_float(__float_as_uint((X1).y) & 0xFFFF0000u);    \
    float l6 = (X1).z - __uint_as_float(__float_as_uint((X1).z) & 0xFFFF0000u);    \
    float l7 = (X1).w - __uint_as_float(__float_as_uint((X1).w) & 0xFFFF0000u);    \
    al.u[0] = perm_hi(l1, l0);                                                     \
    al.u[1] = perm_hi(l3, l2);                                                     \
    al.u[2] = perm_hi(l5, l4);                                                     \
    al.u[3] = perm_hi(l7, l6);                                                     \
    acc = __builtin_amdgcn_mfma_f32_16x16x32_bf16(ah.v, bhi, acc, 0, 0, 0);        \
    acc = __builtin_amdgcn_mfma_f32_16x16x32_bf16(ah.v, blo, acc, 0, 0, 0);        \
    acc = __builtin_amdgcn_mfma_f32_16x16x32_bf16(al.v, bhi, acc, 0, 0, 0);        \
  }

  {
    float4 X0a = ntload4(abase + 0 * 32);
    float4 X0b = ntload4(abase + 0 * 32 + 4);
    float4 X1a = ntload4(abase + 1 * 32);
    float4 X1b = ntload4(abase + 1 * 32 + 4);
    float4 X2a, X2b, X3a, X3b;
    for (int s = 0; s < 16; s += 4) {
      {
        const int r = s + 2;  // <= 14
        X2a = ntload4(abase + r * 32);
        X2b = ntload4(abase + r * 32 + 4);
      }
      COMP(X0a, X0b, s);
      {
        const int r = s + 3;  // <= 15
        X3a = ntload4(abase + r * 32);
        X3b = ntload4(abase + r * 32 + 4);
      }
      COMP(X1a, X1b, s + 1);
      {
        const int r = (s + 4 < 16) ? s + 4 : 15;
        X0a = ntload4(abase + r * 32);
        X0b = ntload4(abase + r * 32 + 4);
      }
      COMP(X2a, X2b, s + 2);
      {
        const int r = (s + 5 < 16) ? s + 5 : 15;
        X1a = ntload4(abase + r * 32);
        X1b = ntload4(abase + r * 32 + 4);
      }
      COMP(X3a, X3b, s + 3);
    }
  }
#undef COMP

  // D: local row = wave*16 + kgrp*4 + i, col = rowL (= e)
  if (rowL < 12) {
    const int lr0 = wave * 16 + kgrp * 4;
#pragma unroll
    for (int i = 0; i < 4; ++i) kpL[lr0 + i][rowL] = acc[i];
  }
  __syncthreads();

  // ---- Phase 2: tail, waves 0..3, one batch each ----
  if (wave < 4) {
    float(*qcS)[28] = (float(*)[28])(smemA + (size_t)wave * (24 * 28 * 4));
    float(*GS)[12] = (float(*)[12])(smemA + 4 * (24 * 28 * 4) + (size_t)wave * (24 * 12 * 4));

    const int b = blockIdx.x * 4 + wave;
    const int li = (lane < 24) ? lane : 0;
    const bool act = (lane < 24);
    const int kb0 = wave * 24;  // this batch's kp rows in kpL

    const float4* WqV = reinterpret_cast<const float4*>(Wq);
    const float4* WlV = reinterpret_cast<const float4*>(Wl);

    // q row -> regs (per-lane, streamed once -> non-temporal)
    float qr[12];
    if (act) {
      const float* qb = q + (size_t)b * 288 + li * 12;
      float4 t0 = ntload4(qb + 0), t1 = ntload4(qb + 4), t2 = ntload4(qb + 8);
      qr[0] = t0.x; qr[1] = t0.y; qr[2] = t0.z; qr[3] = t0.w;
      qr[4] = t1.x; qr[5] = t1.y; qr[6] = t1.z; qr[7] = t1.w;
      qr[8] = t2.x; qr[9] = t2.y; qr[10] = t2.z; qr[11] = t2.w;
    } else {
#pragma unroll
      for (int d = 0; d < 12; ++d) qr[d] = 0.f;
    }

    // q_proj (Wq/bq wave-uniform -> scalar loads)
    float qp_[12];
#pragma unroll
    for (int e = 0; e < 12; ++e) {
      float4 w0 = WqV[e * 3 + 0], w1 = WqV[e * 3 + 1], w2 = WqV[e * 3 + 2];
      qp_[e] = bq[e] + dot12(qr, w0, w1, w2);
    }

    float qbk = 0.f;
#pragma unroll
    for (int e = 0; e < 12; ++e) qbk += qp_[e] * bk[e];

    // qk row: kp rows uniform ds_read from LDS
    float qkr[24];
#pragma unroll
    for (int kk = 0; kk < 24; ++kk) {
      float4 k0 = *(const float4*)&kpL[kb0 + kk][0];
      float4 k1 = *(const float4*)&kpL[kb0 + kk][4];
      float4 k2 = *(const float4*)&kpL[kb0 + kk][8];
      qkr[kk] = qbk + dot12(qp_, k0, k1, k2);
    }
    if (lane >= 24) {
#pragma unroll
      for (int j = 0; j < 24; ++j) qkr[j] = -1e30f;
    }

    // a_k: softmax over kk (registers)
    float akr[24];
    {
      float rm = qkr[0];
#pragma unroll
      for (int j = 1; j < 24; ++j) rm = fmaxf(rm, qkr[j]);
      float s = 0.f;
#pragma unroll
      for (int j = 0; j < 24; ++j) {
        akr[j] = __expf(qkr[j] - rm);
        s += akr[j];
      }
      const float inv = __builtin_amdgcn_rcpf(s);
#pragma unroll
      for (int j = 0; j < 24; ++j) akr[j] *= inv;
    }

    // a_q: softmax over q (32-lane-local butterflies; lanes 24..31 are -1e30)
    if (lane < 32) {
#pragma unroll
      for (int j = 0; j < 24; ++j) {
        const float m = bf32_max(qkr[j]);
        const float t = __expf(qkr[j] - m);
        const float s2 = bf32_add(t);
        qkr[j] = t * __builtin_amdgcn_rcpf(s2);  // a_q row
      }
    }

    // c_q = sum_k a_q*kp + bk*sum(a_q)
    float sa = 0.f;
#pragma unroll
    for (int j = 0; j < 24; ++j) sa += qkr[j];
    float cq[12];
#pragma unroll
    for (int e = 0; e < 12; ++e) cq[e] = bk[e] * sa;
#pragma unroll
    for (int kk = 0; kk < 24; ++kk) {
      float4 k0 = *(const float4*)&kpL[kb0 + kk][0];
      float4 k1 = *(const float4*)&kpL[kb0 + kk][4];
      float4 k2 = *(const float4*)&kpL[kb0 + kk][8];
      const float a = qkr[kk];
      cq[0] += a * k0.x; cq[1] += a * k0.y; cq[2] += a * k0.z; cq[3] += a * k0.w;
      cq[4] += a * k1.x; cq[5] += a * k1.y; cq[6] += a * k1.z; cq[7] += a * k1.w;
      cq[8] += a * k2.x; cq[9] += a * k2.y; cq[10] += a * k2.z; cq[11] += a * k2.w;
    }

    // G[li][d] = sum_kk akr[kk]*Wl[d][kk] (Wl wave-uniform -> scalar)
    float G[12];
#pragma unroll
    for (int d = 0; d < 12; ++d) {
      float4 w0 = WlV[d * 6 + 0], w1 = WlV[d * 6 + 1], w2 = WlV[d * 6 + 2];
      float4 w3 = WlV[d * 6 + 3], w4 = WlV[d * 6 + 4], w5 = WlV[d * 6 + 5];
      G[d] = akr[0] * w0.x + akr[1] * w0.y + akr[2] * w0.z + akr[3] * w0.w +
             akr[4] * w1.x + akr[5] * w1.y + akr[6] * w1.z + akr[7] * w1.w +
             akr[8] * w2.x + akr[9] * w2.y + akr[10] * w2.z + akr[11] * w2.w +
             akr[12] * w3.x + akr[13] * w3.y + akr[14] * w3.z + akr[15] * w3.w +
             akr[16] * w4.x + akr[17] * w4.y + akr[18] * w4.z + akr[19] * w4.w +
             akr[20] * w5.x + akr[21] * w5.y + akr[22] * w5.z + akr[23] * w5.w;
    }

    // stage [q|c_q] and G rows into overlaid LDS (per-wave region)
    if (act) {
      float4 t;
      t.x = qr[0]; t.y = qr[1]; t.z = qr[2]; t.w = qr[3];
      *(float4*)&qcS[li][0] = t;
      t.x = qr[4]; t.y = qr[5]; t.z = qr[6]; t.w = qr[7];
      *(float4*)&qcS[li][4] = t;
      t.x = qr[8]; t.y = qr[9]; t.z = qr[10]; t.w = qr[11];
      *(float4*)&qcS[li][8] = t;
      t.x = cq[0]; t.y = cq[1]; t.z = cq[2]; t.w = cq[3];
      *(float4*)&qcS[li][12] = t;
      t.x = cq[4]; t.y = cq[5]; t.z = cq[6]; t.w = cq[7];
      *(float4*)&qcS[li][16] = t;
      t.x = cq[8]; t.y = cq[9]; t.z = cq[10]; t.w = cq[11];
      *(float4*)&qcS[li][20] = t;
      t.x = G[0]; t.y = G[1]; t.z = G[2]; t.w = G[3];
      *(float4*)&GS[li][0] = t;
      t.x = G[4]; t.y = G[5]; t.z = G[6]; t.w = G[7];
      *(float4*)&GS[li][4] = t;
      t.x = G[8]; t.y = G[9]; t.z = G[10]; t.w = G[11];
      *(float4*)&GS[li][8] = t;
    }

    // attn[e'][d] = bl[d] + sum_q qcS[q][e'] * GS[q][d]  (lane e' = li)
    if (act) {
      float accq[12];
#pragma unroll
      for (int d = 0; d < 12; ++d) accq[d] = bl[d];
#pragma unroll
      for (int q0 = 0; q0 < 24; ++q0) {
        const float qv = qcS[q0][li];
        float4 g0 = *(const float4*)&GS[q0][0];
        float4 g1 = *(const float4*)&GS[q0][4];
        float4 g2 = *(const float4*)&GS[q0][8];
        accq[0] += qv * g0.x; accq[1] += qv * g0.y; accq[2] += qv * g0.z; accq[3] += qv * g0.w;
        accq[4] += qv * g1.x; accq[5] += qv * g1.y; accq[6] += qv * g1.z; accq[7] += qv * g1.w;
        accq[8] += qv * g2.x; accq[9] += qv * g2.y; accq[10] += qv * g2.z; accq[11] += qv * g2.w;
      }
      float* ob = out + (size_t)b * 288 + li * 12;
      float4 w0, w1, w2;
      w0.x = accq[0]; w0.y = accq[1]; w0.z = accq[2]; w0.w = accq[3];
      w1.x = accq[4]; w1.y = accq[5]; w1.z = accq[6]; w1.w = accq[7];
      w2.x = accq[8]; w2.y = accq[9]; w2.z = accq[10]; w2.w = accq[11];
      ntstore4(ob + 0, w0);
      ntstore4(ob + 4, w1);
      ntstore4(ob + 8, w2);
    }
  }
}

// ---------------------------------------------------------------------------
// Fallback: R3 fused one-wave kernel (any B)
// ---------------------------------------------------------------------------
__global__ __launch_bounds__(64) void coattn_kernel(
    const float* __restrict__ q, const float* __restrict__ k,
    const float* __restrict__ Wq, const float* __restrict__ bq,
    const float* __restrict__ Wk, const float* __restrict__ bk,
    const float* __restrict__ Wl, const float* __restrict__ bl,
    float* __restrict__ out) {
  constexpr int QL = 24, KVL = 24, DQ = 12, DKV = 512;

  __shared__ alignas(16) float kp[KVL][DQ];
  __shared__ alignas(16) float qc[QL][24];
  __shared__ alignas(16) float akT[KVL][28];
  __shared__ alignas(16) float ckL[KVL][28];
  __shared__ alignas(16) float WqL[DQ][DQ];
  __shared__ alignas(16) float WlT[KVL][DQ];
  __shared__ alignas(16) float bqL[DQ], bkL[DQ], blL[DQ];

  const int lane = threadIdx.x;
  const int b = blockIdx.x;
  const int li = (lane < 24) ? lane : 0;

  for (int p = lane; p < DQ * DQ; p += 64) WqL[p / DQ][p % DQ] = Wq[p];
  for (int p = lane; p < DQ * KVL; p += 64) WlT[p % KVL][p / KVL] = Wl[p];
  const float* qb = q + (size_t)b * (QL * DQ);
  for (int p = lane; p < QL * DQ; p += 64) qc[p / DQ][p % DQ] = qb[p];
  if (lane < DQ) {
    bqL[lane] = bq[lane];
    bkL[lane] = bk[lane];
    blL[lane] = bl[lane];
  }

  const float4* WkV = reinterpret_cast<const float4*>(Wk);
  float4 wk0[DQ], wk1[DQ];
#pragma unroll
  for (int e = 0; e < DQ; ++e) {
    wk0[e] = WkV[e * 128 + lane];
    wk1[e] = WkV[e * 128 + 64 + lane];
  }

  const float4* kbV = reinterpret_cast<const float4*>(k + (size_t)b * (KVL * DKV));

#define KROW(AC, BC, ROW)                                                          \
  {                                                                                \
    float pp[DQ];                                                                  \
    _Pragma("unroll") for (int e = 0; e < DQ; ++e) {                               \
      pp[e] = (AC).x * wk0[e].x + (AC).y * wk0[e].y + (AC).z * wk0[e].z +          \
              (AC).w * wk0[e].w + (BC).x * wk1[e].x + (BC).y * wk1[e].y +          \
              (BC).z * wk1[e].z + (BC).w * wk1[e].w;                               \
    }                                                                              \
    _Pragma("unroll") for (int e = 0; e < DQ; ++e) pp[e] = wave_sum64(pp[e]);      \
    if (lane == 63) {                                                              \
      float4 w0, w1, w2;                                                           \
      w0.x = pp[0]; w0.y = pp[1]; w0.z = pp[2]; w0.w = pp[3];                      \
      w1.x = pp[4]; w1.y = pp[5]; w1.z = pp[6]; w1.w = pp[7];                      \
      w2.x = pp[8]; w2.y = pp[9]; w2.z = pp[10]; w2.w = pp[11];                    \
      *(float4*)&kp[ROW][0] = w0;                                                  \
      *(float4*)&kp[ROW][4] = w1;                                                  \
      *(float4*)&kp[ROW][8] = w2;                                                  \
    }                                                                              \
  }

  float4 A0 = kbV[0 * 128 + lane], B0 = kbV[0 * 128 + 64 + lane];
  float4 A1 = kbV[1 * 128 + lane], B1 = kbV[1 * 128 + 64 + lane];
  float4 A2, B2, A3, B3;
  for (int kv = 0; kv < KVL; kv += 4) {
    {
      const int r = kv + 2;
      A2 = kbV[r * 128 + lane];
      B2 = kbV[r * 128 + 64 + lane];
    }
    KROW(A0, B0, kv);
    {
      const int r = kv + 3;
      A3 = kbV[r * 128 + lane];
      B3 = kbV[r * 128 + 64 + lane];
    }
    KROW(A1, B1, kv + 1);
    {
      const int r = (kv + 4 < KVL) ? kv + 4 : KVL - 1;
      A0 = kbV[r * 128 + lane];
      B0 = kbV[r * 128 + 64 + lane];
    }
    KROW(A2, B2, kv + 2);
    {
      const int r = (kv + 5 < KVL) ? kv + 5 : KVL - 1;
      A1 = kbV[r * 128 + lane];
      B1 = kbV[r * 128 + 64 + lane];
    }
    KROW(A3, B3, kv + 3);
  }
#undef KROW

  float qr[DQ];
  {
    float4 t0 = *(const float4*)&qc[li][0];
    float4 t1 = *(const float4*)&qc[li][4];
    float4 t2 = *(const float4*)&qc[li][8];
    qr[0] = t0.x; qr[1] = t0.y; qr[2] = t0.z; qr[3] = t0.w;
    qr[4] = t1.x; qr[5] = t1.y; qr[6] = t1.z; qr[7] = t1.w;
    qr[8] = t2.x; qr[9] = t2.y; qr[10] = t2.z; qr[11] = t2.w;
  }
  float bqr[DQ];
  {
    float4 t0 = *(const float4*)&bqL[0];
    float4 t1 = *(const float4*)&bqL[4];
    float4 t2 = *(const float4*)&bqL[8];
    bqr[0] = t0.x; bqr[1] = t0.y; bqr[2] = t0.z; bqr[3] = t0.w;
    bqr[4] = t1.x; bqr[5] = t1.y; bqr[6] = t1.z; bqr[7] = t1.w;
    bqr[8] = t2.x; bqr[9] = t2.y; bqr[10] = t2.z; bqr[11] = t2.w;
  }
  float qp_[DQ];
#pragma unroll
  for (int e = 0; e < DQ; ++e) {
    float4 w0 = *(const float4*)&WqL[e][0];
    float4 w1 = *(const float4*)&WqL[e][4];
    float4 w2 = *(const float4*)&WqL[e][8];
    qp_[e] = bqr[e] + dot12(qr, w0, w1, w2);
  }

  float bkr[DQ];
  {
    float4 t0 = *(const float4*)&bkL[0];
    float4 t1 = *(const float4*)&bkL[4];
    float4 t2 = *(const float4*)&bkL[8];
    bkr[0] = t0.x; bkr[1] = t0.y; bkr[2] = t0.z; bkr[3] = t0.w;
    bkr[4] = t1.x; bkr[5] = t1.y; bkr[6] = t1.z; bkr[7] = t1.w;
    bkr[8] = t2.x; bkr[9] = t2.y; bkr[10] = t2.z; bkr[11] = t2.w;
  }
  float qbk = 0.f;
#pragma unroll
  for (int e = 0; e < DQ; ++e) qbk += qp_[e] * bkr[e];

  float qkr[KVL];
#pragma unroll
  for (int kk = 0; kk < KVL; ++kk) {
    float4 k0 = *(const float4*)&kp[kk][0];
    float4 k1 = *(const float4*)&kp[kk][4];
    float4 k2 = *(const float4*)&kp[kk][8];
    qkr[kk] = qbk + dot12(qp_, k0, k1, k2);
  }
  if (lane >= 24 && lane < 32) {
#pragma unroll
    for (int j = 0; j < KVL; ++j) qkr[j] = -1e30f;
  }

  float akr[KVL];
  {
    float rm = qkr[0];
#pragma unroll
    for (int j = 1; j < KVL; ++j) rm = fmaxf(rm, qkr[j]);
    float s = 0.f;
#pragma unroll
    for (int j = 0; j < KVL; ++j) {
      akr[j] = __expf(qkr[j] - rm);
      s += akr[j];
    }
    const float inv = __builtin_amdgcn_rcpf(s);
#pragma unroll
    for (int j = 0; j < KVL; ++j) akr[j] *= inv;
  }

#pragma unroll
  for (int j = 0; j < KVL; ++j) {
    const float m = bf32_max(qkr[j]);
    const float t = __expf(qkr[j] - m);
    const float s2 = bf32_add(t);
    qkr[j] = t * __builtin_amdgcn_rcpf(s2);
  }

  float sa = 0.f;
#pragma unroll
  for (int j = 0; j < KVL; ++j) sa += qkr[j];
  float cq[DQ];
#pragma unroll
  for (int e = 0; e < DQ; ++e) cq[e] = bkr[e] * sa;
#pragma unroll
  for (int kk = 0; kk < KVL; ++kk) {
    float4 k0 = *(const float4*)&kp[kk][0];
    float4 k1 = *(const float4*)&kp[kk][4];
    float4 k2 = *(const float4*)&kp[kk][8];
    const float a = qkr[kk];
    cq[0] += a * k0.x; cq[1] += a * k0.y; cq[2] += a * k0.z; cq[3] += a * k0.w;
    cq[4] += a * k1.x; cq[5] += a * k1.y; cq[6] += a * k1.z; cq[7] += a * k1.w;
    cq[8] += a * k2.x; cq[9] += a * k2.y; cq[10] += a * k2.z; cq[11] += a * k2.w;
  }
  if (lane < 24) {
    float4 w0, w1, w2;
    w0.x = cq[0]; w0.y = cq[1]; w0.z = cq[2]; w0.w = cq[3];
    w1.x = cq[4]; w1.y = cq[5]; w1.z = cq[6]; w1.w = cq[7];
    w2.x = cq[8]; w2.y = cq[9]; w2.z = cq[10]; w2.w = cq[11];
    *(float4*)&qc[li][12] = w0;
    *(float4*)&qc[li][16] = w1;
    *(float4*)&qc[li][20] = w2;
#pragma unroll
    for (int kk = 0; kk < KVL; ++kk) akT[kk][li] = akr[kk];
  }

  float ak[QL];
  {
    float4 a0 = *(const float4*)&akT[li][0];
    float4 a1 = *(const float4*)&akT[li][4];
    float4 a2 = *(const float4*)&akT[li][8];
    float4 a3 = *(const float4*)&akT[li][12];
    float4 a4 = *(const float4*)&akT[li][16];
    float4 a5 = *(const float4*)&akT[li][20];
    ak[0] = a0.x; ak[1] = a0.y; ak[2] = a0.z; ak[3] = a0.w;
    ak[4] = a1.x; ak[5] = a1.y; ak[6] = a1.z; ak[7] = a1.w;
    ak[8] = a2.x; ak[9] = a2.y; ak[10] = a2.z; ak[11] = a2.w;
    ak[12] = a3.x; ak[13] = a3.y; ak[14] = a3.z; ak[15] = a3.w;
    ak[16] = a4.x; ak[17] = a4.y; ak[18] = a4.z; ak[19] = a4.w;
    ak[20] = a5.x; ak[21] = a5.y; ak[22] = a5.z; ak[23] = a5.w;
  }
  float ck[24];
#pragma unroll
  for (int e = 0; e < 24; ++e) ck[e] = 0.f;
#pragma unroll
  for (int qq = 0; qq < QL; ++qq) {
    float4 c0 = *(const float4*)&qc[qq][0];
    float4 c1 = *(const float4*)&qc[qq][4];
    float4 c2 = *(const float4*)&qc[qq][8];
    float4 c3 = *(const float4*)&qc[qq][12];
    float4 c4 = *(const float4*)&qc[qq][16];
    float4 c5 = *(const float4*)&qc[qq][20];
    const float a = ak[qq];
    ck[0] += a * c0.x; ck[1] += a * c0.y; ck[2] += a * c0.z; ck[3] += a * c0.w;
    ck[4] += a * c1.x; ck[5] += a * c1.y; ck[6] += a * c1.z; ck[7] += a * c1.w;
    ck[8] += a * c2.x; ck[9] += a * c2.y; ck[10] += a * c2.z; ck[11] += a * c2.w;
    ck[12] += a * c3.x; ck[13] += a * c3.y; ck[14] += a * c3.z; ck[15] += a * c3.w;
    ck[16] += a * c4.x; ck[17] += a * c4.y; ck[18] += a * c4.z; ck[19] += a * c4.w;
    ck[20] += a * c5.x; ck[21] += a * c5.y; ck[22] += a * c5.z; ck[23] += a * c5.w;
  }
  if (lane < 24) {
    float4 w0, w1, w2, w3, w4, w5;
    w0.x = ck[0]; w0.y = ck[1]; w0.z = ck[2]; w0.w = ck[3];
    w1.x = ck[4]; w1.y = ck[5]; w1.z = ck[6]; w1.w = ck[7];
    w2.x = ck[8]; w2.y = ck[9]; w2.z = ck[10]; w2.w = ck[11];
    w3.x = ck[12]; w3.y = ck[13]; w3.z = ck[14]; w3.w = ck[15];
    w4.x = ck[16]; w4.y = ck[17]; w4.z = ck[18]; w4.w = ck[19];
    w5.x = ck[20]; w5.y = ck[21]; w5.z = ck[22]; w5.w = ck[23];
    *(float4*)&ckL[li][0] = w0;
    *(float4*)&ckL[li][4] = w1;
    *(float4*)&ckL[li][8] = w2;
    *(float4*)&ckL[li][12] = w3;
    *(float4*)&ckL[li][16] = w4;
    *(float4*)&ckL[li][20] = w5;
  }

  float acc[DQ];
  {
    float4 t0 = *(const float4*)&blL[0];
    float4 t1 = *(const float4*)&blL[4];
    float4 t2 = *(const float4*)&blL[8];
    acc[0] = t0.x; acc[1] = t0.y; acc[2] = t0.z; acc[3] = t0.w;
    acc[4] = t1.x; acc[5] = t1.y; acc[6] = t1.z; acc[7] = t1.w;
    acc[8] = t2.x; acc[9] = t2.y; acc[10] = t2.z; acc[11] = t2.w;
  }
#pragma unroll
  for (int kk = 0; kk < KVL; ++kk) {
    const float cv = ckL[kk][li];
    float4 w0 = *(const float4*)&WlT[kk][0];
    float4 w1 = *(const float4*)&WlT[kk][4];
    float4 w2 = *(const float4*)&WlT[kk][8];
    acc[0] += cv * w0.x; acc[1] += cv * w0.y; acc[2] += cv * w0.z; acc[3] += cv * w0.w;
    acc[4] += cv * w1.x; acc[5] += cv * w1.y; acc[6] += cv * w1.z; acc[7] += cv * w1.w;
    acc[8] += cv * w2.x; acc[9] += cv * w2.y; acc[10] += cv * w2.z; acc[11] += cv * w2.w;
  }
  if (lane < 24) {
    float* ob = out + (size_t)b * 288 + li * 12;
    float4 w0, w1, w2;
    w0.x = acc[0]; w0.y = acc[1]; w0.z = acc[2]; w0.w = acc[3];
    w1.x = acc[4]; w1.y = acc[5]; w1.z = acc[6]; w1.w = acc[7];
    w2.x = acc[8]; w2.y = acc[9]; w2.z = acc[10]; w2.w = acc[11];
    *(float4*)(ob + 0) = w0;
    *(float4*)(ob + 4) = w1;
    *(float4*)(ob + 8) = w2;
  }
}

extern "C" void kernel_launch(void* const* d_in, const int* in_sizes, int n_in,
                              void* d_out, int out_size, void* d_ws, size_t ws_size,
                              hipStream_t stream) {
  const float* q = (const float*)d_in[0];
  const float* k = (const float*)d_in[1];
  // d_in[2] = v : unused by the reference
  const float* Wq = (const float*)d_in[3];
  const float* bq = (const float*)d_in[4];
  const float* Wk = (const float*)d_in[5];
  const float* bk = (const float*)d_in[6];
  const float* Wl = (const float*)d_in[7];
  const float* bl = (const float*)d_in[8];
  float* out = (float*)d_out;

  const int B = in_sizes[0] / (24 * 12);

  if ((B % 4) == 0) {
    coattn_fused<<<B / 4, 384, 0, stream>>>(q, k, Wq, bq, Wk, bk, Wl, bl, out);
  } else {
    coattn_kernel<<<B, 64, 0, stream>>>(q, k, Wq, bq, Wk, bk, Wl, bl, out);
  }
}